// Round 1
// baseline (1329.240 us; speedup 1.0000x reference)
//
#include <hip/hip_runtime.h>
#include <hip/hip_bf16.h>
#include <math.h>

#define Bn   8
#define Sn   512
#define HIDn 768
#define Hn   12
#define DHn  64
#define Tn   (Bn * Sn)   // 4096

// d_out float plane offsets (elements), return order:
// (context_layer, attention_scores, value_scores, query_scores, key_scores)
#define OFF_CTX   0ull
#define OFF_ATTN  3145728ull     // 8*512*768
#define OFF_VAL   28311552ull    // + 8*12*512*512
#define OFF_QRY   53477376ull
#define OFF_KEY   78643200ull

__device__ __forceinline__ float sgnf(float x) {
    return (x > 0.0f) ? 1.0f : ((x < 0.0f) ? -1.0f : 0.0f);
}

// ---------------------------------------------------------------------------
// K1: QKV projection.  C[t][j] = hidden[t,:] . W[j,:] + b[j]
// C is [4096, 2304] where cols 0-767 -> Q, 768-1535 -> K, 1536-2303 -> V.
// 64x64 tile, BK=32, 256 threads, 4x4 per thread, fp32 FMA.
// Near-zero results (|v| < 1e-3) are re-accumulated in fp64 so that
// sign(q/k/v) matches the high-precision reference exactly.
// ---------------------------------------------------------------------------
__global__ __launch_bounds__(256) void proj_kernel(
    const float* __restrict__ hid,
    const float* __restrict__ Wq, const float* __restrict__ bq,
    const float* __restrict__ Wk, const float* __restrict__ bk,
    const float* __restrict__ Wv, const float* __restrict__ bv,
    float* __restrict__ qkv /* [3][Tn][HIDn] */)
{
    __shared__ float As[64][36];   // +4 pad: keeps float4 alignment, spreads banks
    __shared__ float Ws[64][36];

    const int j0 = blockIdx.x * 64;          // 0..2240
    const int t0 = blockIdx.y * 64;          // 0..4032
    const int which = j0 / HIDn;             // 0=q 1=k 2=v
    const int jw0 = j0 % HIDn;
    const float* W    = (which == 0) ? Wq : (which == 1) ? Wk : Wv;
    const float* bias = (which == 0) ? bq : (which == 1) ? bk : bv;

    const int tid = threadIdx.x;
    const int tx = tid & 15, ty = tid >> 4;

    float acc[4][4] = {};
    for (int kb = 0; kb < HIDn; kb += 32) {
        #pragma unroll
        for (int l = 0; l < 2; ++l) {
            int f  = tid + l * 256;          // 0..511
            int r  = f >> 3;                 // 64 rows, 8 float4 per row
            int c4 = (f & 7) << 2;
            *(float4*)&As[r][c4] = *(const float4*)&hid[(size_t)(t0 + r) * HIDn + kb + c4];
            *(float4*)&Ws[r][c4] = *(const float4*)&W  [(size_t)(jw0 + r) * HIDn + kb + c4];
        }
        __syncthreads();
        #pragma unroll
        for (int k4 = 0; k4 < 8; ++k4) {
            float4 a4[4], w4[4];
            #pragma unroll
            for (int i = 0; i < 4; ++i) a4[i] = *(const float4*)&As[ty * 4 + i][k4 * 4];
            #pragma unroll
            for (int j = 0; j < 4; ++j) w4[j] = *(const float4*)&Ws[tx * 4 + j][k4 * 4];
            #pragma unroll
            for (int i = 0; i < 4; ++i)
                #pragma unroll
                for (int j = 0; j < 4; ++j) {
                    acc[i][j] = fmaf(a4[i].x, w4[j].x, acc[i][j]);
                    acc[i][j] = fmaf(a4[i].y, w4[j].y, acc[i][j]);
                    acc[i][j] = fmaf(a4[i].z, w4[j].z, acc[i][j]);
                    acc[i][j] = fmaf(a4[i].w, w4[j].w, acc[i][j]);
                }
        }
        __syncthreads();
    }

    #pragma unroll
    for (int i = 0; i < 4; ++i) {
        const int t = t0 + ty * 4 + i;
        #pragma unroll
        for (int j = 0; j < 4; ++j) {
            const int jw = jw0 + tx * 4 + j;
            float v = acc[i][j] + bias[jw];
            if (fabsf(v) < 1e-3f) {
                // rare (~0.08% of elements): exact-sign fp64 re-accumulation
                double d = (double)bias[jw];
                const float* arow = &hid[(size_t)t * HIDn];
                const float* wrow = &W[(size_t)jw * HIDn];
                for (int k = 0; k < HIDn; ++k)
                    d += (double)arow[k] * (double)wrow[k];
                v = (float)d;
            }
            qkv[(size_t)which * Tn * HIDn + (size_t)t * HIDn + jw] = v;
        }
    }
}

// ---------------------------------------------------------------------------
// K2: the four S x S score matrices per (b,h).
// which: 0 -> q.q  (query_scores), 1 -> k.k (key_scores),
//        2 -> v.v  (value_scores), 3 -> sign(q).sign(k) + mask (attention_scores)
// 64x64 output tile, K = DH = 64 in one shot.
// ---------------------------------------------------------------------------
__global__ __launch_bounds__(256) void scores_kernel(
    const float* __restrict__ qkv, const float* __restrict__ mask,
    float* __restrict__ out)
{
    __shared__ float As[64][68];
    __shared__ float Bs[64][68];

    const int which = blockIdx.z;
    const int bh = blockIdx.y;
    const int b = bh / Hn, h = bh % Hn;
    const int s0 = (blockIdx.x >> 3) << 6;
    const int t0 = (blockIdx.x & 7) << 6;

    int pa, pb;
    if (which == 3) { pa = 0; pb = 1; } else { pa = which; pb = which; }
    const float* Ap = qkv + (size_t)pa * Tn * HIDn + (size_t)(b * Sn + s0) * HIDn + h * DHn;
    const float* Bp = qkv + (size_t)pb * Tn * HIDn + (size_t)(b * Sn + t0) * HIDn + h * DHn;

    const int tid = threadIdx.x;
    #pragma unroll
    for (int l = 0; l < 4; ++l) {
        int f  = tid + l * 256;              // 0..1023
        int r  = f >> 4;                     // 64 rows, 16 float4 per row
        int c4 = (f & 15) << 2;
        float4 va = *(const float4*)(Ap + (size_t)r * HIDn + c4);
        float4 vb = *(const float4*)(Bp + (size_t)r * HIDn + c4);
        if (which == 3) {
            va.x = sgnf(va.x); va.y = sgnf(va.y); va.z = sgnf(va.z); va.w = sgnf(va.w);
            vb.x = sgnf(vb.x); vb.y = sgnf(vb.y); vb.z = sgnf(vb.z); vb.w = sgnf(vb.w);
        }
        *(float4*)&As[r][c4] = va;
        *(float4*)&Bs[r][c4] = vb;
    }
    __syncthreads();

    const int tx = tid & 15, ty = tid >> 4;
    float acc[4][4] = {};
    #pragma unroll
    for (int k4 = 0; k4 < 16; ++k4) {
        float4 a4[4], b4[4];
        #pragma unroll
        for (int i = 0; i < 4; ++i) a4[i] = *(const float4*)&As[ty * 4 + i][k4 * 4];
        #pragma unroll
        for (int j = 0; j < 4; ++j) b4[j] = *(const float4*)&Bs[tx * 4 + j][k4 * 4];
        #pragma unroll
        for (int i = 0; i < 4; ++i)
            #pragma unroll
            for (int j = 0; j < 4; ++j) {
                acc[i][j] = fmaf(a4[i].x, b4[j].x, acc[i][j]);
                acc[i][j] = fmaf(a4[i].y, b4[j].y, acc[i][j]);
                acc[i][j] = fmaf(a4[i].z, b4[j].z, acc[i][j]);
                acc[i][j] = fmaf(a4[i].w, b4[j].w, acc[i][j]);
            }
    }

    const size_t plane = (which == 0) ? OFF_QRY : (which == 1) ? OFF_KEY
                       : (which == 2) ? OFF_VAL : OFF_ATTN;
    float* o = out + plane + (size_t)bh * Sn * Sn;
    #pragma unroll
    for (int i = 0; i < 4; ++i) {
        const int srow = s0 + ty * 4 + i;
        #pragma unroll
        for (int j = 0; j < 4; ++j) {
            const int tcol = t0 + tx * 4 + j;
            float v = acc[i][j] * 0.125f;
            if (which == 3) v += mask[b * Sn + tcol];
            o[(size_t)srow * Sn + tcol] = v;
        }
    }
}

// ---------------------------------------------------------------------------
// K3: ctx = probs @ sign(V), probs = (attention_scores > 0) read back from out.
// Per (b,h): C[512,64]. 64-row tile per block, K loop over 512 in 64 chunks.
// ---------------------------------------------------------------------------
__global__ __launch_bounds__(256) void ctx_kernel(
    const float* __restrict__ qkv, const float* __restrict__ outc,
    float* __restrict__ out0)
{
    __shared__ float Ps[64][68];
    __shared__ float Vs[64][68];   // Vs[k][d]

    const int bh = blockIdx.y;
    const int b = bh / Hn, h = bh % Hn;
    const int s0 = blockIdx.x << 6;
    const float* sc = outc + OFF_ATTN + (size_t)bh * Sn * Sn;
    const float* Vp = qkv + 2ull * Tn * HIDn + (size_t)(b * Sn) * HIDn + h * DHn;

    const int tid = threadIdx.x;
    const int tx = tid & 15, ty = tid >> 4;
    float acc[4][4] = {};

    for (int kb = 0; kb < Sn; kb += 64) {
        #pragma unroll
        for (int l = 0; l < 4; ++l) {
            int f  = tid + l * 256;
            int r  = f >> 4;
            int c4 = (f & 15) << 2;
            float4 p = *(const float4*)(sc + (size_t)(s0 + r) * Sn + kb + c4);
            p.x = (p.x > 0.f) ? 1.f : 0.f;
            p.y = (p.y > 0.f) ? 1.f : 0.f;
            p.z = (p.z > 0.f) ? 1.f : 0.f;
            p.w = (p.w > 0.f) ? 1.f : 0.f;
            *(float4*)&Ps[r][c4] = p;
            float4 v = *(const float4*)(Vp + (size_t)(kb + r) * HIDn + c4);
            v.x = sgnf(v.x); v.y = sgnf(v.y); v.z = sgnf(v.z); v.w = sgnf(v.w);
            *(float4*)&Vs[r][c4] = v;
        }
        __syncthreads();
        #pragma unroll
        for (int k = 0; k < 64; ++k) {
            float p[4];
            #pragma unroll
            for (int i = 0; i < 4; ++i) p[i] = Ps[ty * 4 + i][k];
            float4 vv = *(const float4*)&Vs[k][tx * 4];
            #pragma unroll
            for (int i = 0; i < 4; ++i) {
                acc[i][0] = fmaf(p[i], vv.x, acc[i][0]);
                acc[i][1] = fmaf(p[i], vv.y, acc[i][1]);
                acc[i][2] = fmaf(p[i], vv.z, acc[i][2]);
                acc[i][3] = fmaf(p[i], vv.w, acc[i][3]);
            }
        }
        __syncthreads();
    }

    #pragma unroll
    for (int i = 0; i < 4; ++i) {
        const int srow = s0 + ty * 4 + i;
        float4 r4 = make_float4(acc[i][0], acc[i][1], acc[i][2], acc[i][3]);
        *(float4*)(out0 + (size_t)(b * Sn + srow) * HIDn + h * DHn + tx * 4) = r4;
    }
}

extern "C" void kernel_launch(void* const* d_in, const int* in_sizes, int n_in,
                              void* d_out, int out_size, void* d_ws, size_t ws_size,
                              hipStream_t stream)
{
    const float* hid  = (const float*)d_in[0];
    const float* mask = (const float*)d_in[1];
    const float* Wq   = (const float*)d_in[2];
    const float* bq   = (const float*)d_in[3];
    const float* Wk   = (const float*)d_in[4];
    const float* bk   = (const float*)d_in[5];
    const float* Wv   = (const float*)d_in[6];
    const float* bv   = (const float*)d_in[7];
    float* out = (float*)d_out;
    float* qkv = (float*)d_ws;   // 3 * 4096 * 768 fp32 = 37.75 MB

    dim3 blk(256);
    dim3 g1(2304 / 64, Tn / 64);           // 36 x 64
    proj_kernel<<<g1, blk, 0, stream>>>(hid, Wq, bq, Wk, bk, Wv, bv, qkv);

    dim3 g2(64, Bn * Hn, 4);               // 8x8 tiles, 96 bh, 4 matrices
    scores_kernel<<<g2, blk, 0, stream>>>(qkv, mask, out);

    dim3 g3(Sn / 64, Bn * Hn);             // 8 row-tiles, 96 bh
    ctx_kernel<<<g3, blk, 0, stream>>>(qkv, out, out);
}

// Round 2
// 572.550 us; speedup vs baseline: 2.3216x; 2.3216x over previous
//
#include <hip/hip_runtime.h>
#include <hip/hip_bf16.h>
#include <math.h>

#define Bn   8
#define Sn   512
#define HIDn 768
#define Hn   12
#define DHn  64
#define Tn   (Bn * Sn)   // 4096

// d_out float plane offsets (elements), return order:
// (context_layer, attention_scores, value_scores, query_scores, key_scores)
#define OFF_CTX   0ull
#define OFF_ATTN  3145728ull     // 8*512*768
#define OFF_VAL   28311552ull    // + 8*12*512*512
#define OFF_QRY   53477376ull
#define OFF_KEY   78643200ull

typedef short  s8v    __attribute__((ext_vector_type(8)));
typedef short  short4v __attribute__((ext_vector_type(4)));
typedef float  f32x4  __attribute__((ext_vector_type(4)));

#define MFMA(a, b, c) __builtin_amdgcn_mfma_f32_16x16x32_bf16((a), (b), (c), 0, 0, 0)

__device__ __forceinline__ float sgnf(float x) {
    return (x > 0.0f) ? 1.0f : ((x < 0.0f) ? -1.0f : 0.0f);
}
__device__ __forceinline__ unsigned short f2bf(float f) {   // RNE f32 -> bf16 bits
    unsigned int u = __float_as_uint(f);
    u += 0x7fffu + ((u >> 16) & 1u);
    return (unsigned short)(u >> 16);
}
__device__ __forceinline__ float bf2f(unsigned short h) {
    return __uint_as_float(((unsigned int)h) << 16);
}
__device__ __forceinline__ short sgnbf(float x) {           // bf16 bits of sign(x)
    return x > 0.f ? (short)0x3F80 : (x < 0.f ? (short)0xBF80 : (short)0);
}

// ---------------------------------------------------------------------------
// LDS tile: [128 rows][64 k] bf16, byte = row*128 + k*2, XOR-swizzled by
// (row&7)<<4 so stride-128B fragment reads spread across banks (2-way max).
// ---------------------------------------------------------------------------
__device__ __forceinline__ void stage_hl(const float* __restrict__ src, int ld,
                                         unsigned char* Lh, unsigned char* Ll, int tid) {
    #pragma unroll
    for (int it = 0; it < 8; ++it) {
        int f   = tid + it * 256;          // 0..2047 -> 128 rows x 16 float4
        int row = f >> 4;
        int c4  = (f & 15) << 2;
        float4 v = *(const float4*)(src + (size_t)row * ld + c4);
        unsigned short h0 = f2bf(v.x), h1 = f2bf(v.y), h2 = f2bf(v.z), h3 = f2bf(v.w);
        short4v hv = { (short)h0, (short)h1, (short)h2, (short)h3 };
        short4v lv = { (short)f2bf(v.x - bf2f(h0)), (short)f2bf(v.y - bf2f(h1)),
                       (short)f2bf(v.z - bf2f(h2)), (short)f2bf(v.w - bf2f(h3)) };
        int sw = (row * 128 + (c4 << 1)) ^ ((row & 7) << 4);
        *(short4v*)(Lh + sw) = hv;
        *(short4v*)(Ll + sw) = lv;
    }
}
__device__ __forceinline__ void stage_sgn(const float* __restrict__ src, int ld,
                                          unsigned char* Lh, int tid) {
    #pragma unroll
    for (int it = 0; it < 8; ++it) {
        int f   = tid + it * 256;
        int row = f >> 4;
        int c4  = (f & 15) << 2;
        float4 v = *(const float4*)(src + (size_t)row * ld + c4);
        short4v hv = { sgnbf(v.x), sgnbf(v.y), sgnbf(v.z), sgnbf(v.w) };
        int sw = (row * 128 + (c4 << 1)) ^ ((row & 7) << 4);
        *(short4v*)(Lh + sw) = hv;
    }
}
// fragment: 8 contiguous bf16 at row, k = kk*32 + kg*8 (B^T-form, K-perm immune)
__device__ __forceinline__ s8v frag(const unsigned char* P, int row, int kk, int kg) {
    int byte = (row * 128 + kk * 64 + kg * 16) ^ ((row & 7) << 4);
    return *(const s8v*)(P + byte);
}

// ---------------------------------------------------------------------------
// K1: QKV projection via MFMA bf16x3.  C[t][j] = hid[t,:].W[j,:] + b[j].
// 128x128 tile, BK=64, 4 waves (2x2), 4x4 16x16 frags per wave.
// |v| < 1e-3 -> exact fp64 re-accumulation (sign-exact binarization).
// ---------------------------------------------------------------------------
__global__ __launch_bounds__(256) void proj_mfma(
    const float* __restrict__ hid,
    const float* __restrict__ Wq, const float* __restrict__ bq,
    const float* __restrict__ Wk, const float* __restrict__ bk,
    const float* __restrict__ Wv, const float* __restrict__ bv,
    float* __restrict__ qkv)
{
    __shared__ unsigned char sm[65536];   // Ah|Al|Bh|Bl, 16KB each
    const int nb    = blockIdx.x;         // 0..17
    const int which = nb / 6;
    const int jw0   = (nb % 6) * 128;
    const int t0    = blockIdx.y * 128;
    const float* W    = (which == 0) ? Wq : (which == 1) ? Wk : Wv;
    const float* bias = (which == 0) ? bq : (which == 1) ? bk : bv;

    const int tid  = threadIdx.x;
    const int lane = tid & 63;
    const int wv   = tid >> 6;
    const int wm   = wv >> 1, wn = wv & 1;
    const int r    = lane & 15, kg = lane >> 4;

    f32x4 acc[4][4] = {};
    for (int kb = 0; kb < HIDn; kb += 64) {
        stage_hl(hid + (size_t)t0  * HIDn + kb, HIDn, sm,         sm + 16384, tid);
        stage_hl(W   + (size_t)jw0 * HIDn + kb, HIDn, sm + 32768, sm + 49152, tid);
        __syncthreads();
        s8v bH[4][2], bL[4][2];
        #pragma unroll
        for (int n = 0; n < 4; ++n)
            #pragma unroll
            for (int kk = 0; kk < 2; ++kk) {
                int brow = wn * 64 + n * 16 + r;
                bH[n][kk] = frag(sm + 32768, brow, kk, kg);
                bL[n][kk] = frag(sm + 49152, brow, kk, kg);
            }
        #pragma unroll
        for (int m = 0; m < 4; ++m) {
            int arow = wm * 64 + m * 16 + r;
            s8v aH[2], aL[2];
            #pragma unroll
            for (int kk = 0; kk < 2; ++kk) {
                aH[kk] = frag(sm,         arow, kk, kg);
                aL[kk] = frag(sm + 16384, arow, kk, kg);
            }
            #pragma unroll
            for (int n = 0; n < 4; ++n)
                #pragma unroll
                for (int kk = 0; kk < 2; ++kk) {
                    acc[m][n] = MFMA(aH[kk], bH[n][kk], acc[m][n]);
                    acc[m][n] = MFMA(aH[kk], bL[n][kk], acc[m][n]);
                    acc[m][n] = MFMA(aL[kk], bH[n][kk], acc[m][n]);
                }
        }
        __syncthreads();
    }

    #pragma unroll
    for (int n = 0; n < 4; ++n) {
        const int jw = jw0 + wn * 64 + n * 16 + r;
        const float bs = bias[jw];
        #pragma unroll
        for (int m = 0; m < 4; ++m) {
            #pragma unroll
            for (int reg = 0; reg < 4; ++reg) {
                const int t = t0 + wm * 64 + m * 16 + kg * 4 + reg;
                float v = acc[m][n][reg] + bs;
                if (fabsf(v) < 1e-3f) {
                    double d = (double)bs;
                    const float* ar = hid + (size_t)t * HIDn;
                    const float* wr = W + (size_t)jw * HIDn;
                    for (int k = 0; k < HIDn; ++k)
                        d += (double)ar[k] * (double)wr[k];
                    v = (float)d;
                }
                qkv[(size_t)which * (size_t)(Tn * HIDn) + (size_t)t * HIDn + jw] = v;
            }
        }
    }
}

// ---------------------------------------------------------------------------
// K2: four S x S score planes per (b,h) via MFMA.
// which 0/1/2: bf16x3 (hi.hi + hi.lo + lo.hi) fp scores; which 3: exact
// sign(q).sign(k) single-term + mask. 128x128 tile, K=64 in one shot.
// ---------------------------------------------------------------------------
__global__ __launch_bounds__(256) void scores_mfma(
    const float* __restrict__ qkv, const float* __restrict__ mask,
    float* __restrict__ out)
{
    __shared__ unsigned char sm[65536];
    const int which = blockIdx.z;
    const int bh = blockIdx.y;
    const int b = bh / Hn, h = bh % Hn;
    const int s0 = (blockIdx.x >> 2) << 7;
    const int t0 = (blockIdx.x & 3) << 7;
    const int pa = (which == 3) ? 0 : which;
    const int pb = (which == 3) ? 1 : which;
    const float* Ap = qkv + (size_t)pa * (size_t)(Tn * HIDn) + (size_t)(b * Sn + s0) * HIDn + h * DHn;
    const float* Bp = qkv + (size_t)pb * (size_t)(Tn * HIDn) + (size_t)(b * Sn + t0) * HIDn + h * DHn;
    const int tid = threadIdx.x;
    const bool fp = (which != 3);

    if (fp) {
        stage_hl(Ap, HIDn, sm,         sm + 16384, tid);
        stage_hl(Bp, HIDn, sm + 32768, sm + 49152, tid);
    } else {
        stage_sgn(Ap, HIDn, sm,         tid);
        stage_sgn(Bp, HIDn, sm + 32768, tid);
    }
    __syncthreads();

    const int lane = tid & 63;
    const int wv   = tid >> 6;
    const int wm   = wv >> 1, wn = wv & 1;
    const int r    = lane & 15, kg = lane >> 4;

    f32x4 acc[4][4] = {};
    s8v bH[4][2], bL[4][2];
    #pragma unroll
    for (int n = 0; n < 4; ++n)
        #pragma unroll
        for (int kk = 0; kk < 2; ++kk) {
            int brow = wn * 64 + n * 16 + r;
            bH[n][kk] = frag(sm + 32768, brow, kk, kg);
            if (fp) bL[n][kk] = frag(sm + 49152, brow, kk, kg);
        }
    #pragma unroll
    for (int m = 0; m < 4; ++m) {
        int arow = wm * 64 + m * 16 + r;
        s8v aH[2], aL[2];
        #pragma unroll
        for (int kk = 0; kk < 2; ++kk) {
            aH[kk] = frag(sm, arow, kk, kg);
            if (fp) aL[kk] = frag(sm + 16384, arow, kk, kg);
        }
        #pragma unroll
        for (int n = 0; n < 4; ++n)
            #pragma unroll
            for (int kk = 0; kk < 2; ++kk) {
                acc[m][n] = MFMA(aH[kk], bH[n][kk], acc[m][n]);
                if (fp) {
                    acc[m][n] = MFMA(aH[kk], bL[n][kk], acc[m][n]);
                    acc[m][n] = MFMA(aL[kk], bH[n][kk], acc[m][n]);
                }
            }
    }

    const size_t plane = (which == 0) ? OFF_QRY : (which == 1) ? OFF_KEY
                       : (which == 2) ? OFF_VAL : OFF_ATTN;
    float* o = out + plane + (size_t)bh * (size_t)(Sn * Sn);
    #pragma unroll
    for (int n = 0; n < 4; ++n) {
        const int col = t0 + wn * 64 + n * 16 + r;
        const float mk = fp ? 0.f : mask[b * Sn + col];
        #pragma unroll
        for (int m = 0; m < 4; ++m) {
            #pragma unroll
            for (int reg = 0; reg < 4; ++reg) {
                const int srow = s0 + wm * 64 + m * 16 + kg * 4 + reg;
                o[(size_t)srow * Sn + col] = acc[m][n][reg] * 0.125f + mk;
            }
        }
    }
}

// ---------------------------------------------------------------------------
// K3: ctx = probs @ sign(V), probs = (attention_scores > 0) read back from out.
// fp32 vector version (known-good from round 1) — MFMA-ize next round if hot.
// ---------------------------------------------------------------------------
__global__ __launch_bounds__(256) void ctx_kernel(
    const float* __restrict__ qkv, const float* __restrict__ outc,
    float* __restrict__ out0)
{
    __shared__ float Ps[64][68];
    __shared__ float Vs[64][68];   // Vs[k][d]

    const int bh = blockIdx.y;
    const int b = bh / Hn, h = bh % Hn;
    const int s0 = blockIdx.x << 6;
    const float* sc = outc + OFF_ATTN + (size_t)bh * Sn * Sn;
    const float* Vp = qkv + 2ull * Tn * HIDn + (size_t)(b * Sn) * HIDn + h * DHn;

    const int tid = threadIdx.x;
    const int tx = tid & 15, ty = tid >> 4;
    float acc[4][4] = {};

    for (int kb = 0; kb < Sn; kb += 64) {
        #pragma unroll
        for (int l = 0; l < 4; ++l) {
            int f  = tid + l * 256;
            int r  = f >> 4;
            int c4 = (f & 15) << 2;
            float4 p = *(const float4*)(sc + (size_t)(s0 + r) * Sn + kb + c4);
            p.x = (p.x > 0.f) ? 1.f : 0.f;
            p.y = (p.y > 0.f) ? 1.f : 0.f;
            p.z = (p.z > 0.f) ? 1.f : 0.f;
            p.w = (p.w > 0.f) ? 1.f : 0.f;
            *(float4*)&Ps[r][c4] = p;
            float4 v = *(const float4*)(Vp + (size_t)(kb + r) * HIDn + c4);
            v.x = sgnf(v.x); v.y = sgnf(v.y); v.z = sgnf(v.z); v.w = sgnf(v.w);
            *(float4*)&Vs[r][c4] = v;
        }
        __syncthreads();
        #pragma unroll
        for (int k = 0; k < 64; ++k) {
            float p[4];
            #pragma unroll
            for (int i = 0; i < 4; ++i) p[i] = Ps[ty * 4 + i][k];
            float4 vv = *(const float4*)&Vs[k][tx * 4];
            #pragma unroll
            for (int i = 0; i < 4; ++i) {
                acc[i][0] = fmaf(p[i], vv.x, acc[i][0]);
                acc[i][1] = fmaf(p[i], vv.y, acc[i][1]);
                acc[i][2] = fmaf(p[i], vv.z, acc[i][2]);
                acc[i][3] = fmaf(p[i], vv.w, acc[i][3]);
            }
        }
        __syncthreads();
    }

    #pragma unroll
    for (int i = 0; i < 4; ++i) {
        const int srow = s0 + ty * 4 + i;
        float4 r4 = make_float4(acc[i][0], acc[i][1], acc[i][2], acc[i][3]);
        *(float4*)(out0 + (size_t)(b * Sn + srow) * HIDn + h * DHn + tx * 4) = r4;
    }
}

extern "C" void kernel_launch(void* const* d_in, const int* in_sizes, int n_in,
                              void* d_out, int out_size, void* d_ws, size_t ws_size,
                              hipStream_t stream)
{
    const float* hid  = (const float*)d_in[0];
    const float* mask = (const float*)d_in[1];
    const float* Wq   = (const float*)d_in[2];
    const float* bq   = (const float*)d_in[3];
    const float* Wk   = (const float*)d_in[4];
    const float* bk   = (const float*)d_in[5];
    const float* Wv   = (const float*)d_in[6];
    const float* bv   = (const float*)d_in[7];
    float* out = (float*)d_out;
    float* qkv = (float*)d_ws;   // 3 * 4096 * 768 fp32 = 37.75 MB

    dim3 blk(256);
    proj_mfma  <<<dim3(18, 32),    blk, 0, stream>>>(hid, Wq, bq, Wk, bk, Wv, bv, qkv);
    scores_mfma<<<dim3(16, 96, 4), blk, 0, stream>>>(qkv, mask, out);
    ctx_kernel <<<dim3(8, 96),     blk, 0, stream>>>(qkv, out, out);
}

// Round 3
// 487.702 us; speedup vs baseline: 2.7255x; 1.1740x over previous
//
#include <hip/hip_runtime.h>
#include <hip/hip_bf16.h>
#include <math.h>

#define Bn   8
#define Sn   512
#define HIDn 768
#define Hn   12
#define DHn  64
#define Tn   (Bn * Sn)   // 4096

// d_out float plane offsets (elements), return order:
// (context_layer, attention_scores, value_scores, query_scores, key_scores)
#define OFF_CTX   0ull
#define OFF_ATTN  3145728ull     // 8*512*768
#define OFF_VAL   28311552ull    // + 8*12*512*512
#define OFF_QRY   53477376ull
#define OFF_KEY   78643200ull

#define QKV_BYTES 37748736ull    // 3*4096*768*4
#define MAXCAND   65536u

typedef short  s8v     __attribute__((ext_vector_type(8)));
typedef short  short4v __attribute__((ext_vector_type(4)));
typedef float  f32x4   __attribute__((ext_vector_type(4)));

#define MFMA(a, b, c) __builtin_amdgcn_mfma_f32_16x16x32_bf16((a), (b), (c), 0, 0, 0)

__device__ __forceinline__ float sgnf(float x) {
    return (x > 0.0f) ? 1.0f : ((x < 0.0f) ? -1.0f : 0.0f);
}
__device__ __forceinline__ unsigned short f2bf(float f) {   // RNE f32 -> bf16 bits
    unsigned int u = __float_as_uint(f);
    u += 0x7fffu + ((u >> 16) & 1u);
    return (unsigned short)(u >> 16);
}
__device__ __forceinline__ float bf2f(unsigned short h) {
    return __uint_as_float(((unsigned int)h) << 16);
}
__device__ __forceinline__ short sgnbf(float x) {           // bf16 bits of sign(x)
    return x > 0.f ? (short)0x3F80 : (x < 0.f ? (short)0xBF80 : (short)0);
}

// ---------------------------------------------------------------------------
// LDS tile: [128 rows][64 k] bf16, byte = row*128 + k*2, XOR-swizzled by
// (row&7)<<4 so stride-128B fragment reads spread across banks (2-way max).
// ---------------------------------------------------------------------------
__device__ __forceinline__ void stage_hl(const float* __restrict__ src, int ld,
                                         unsigned char* Lh, unsigned char* Ll, int tid) {
    #pragma unroll
    for (int it = 0; it < 8; ++it) {
        int f   = tid + it * 256;          // 0..2047 -> 128 rows x 16 float4
        int row = f >> 4;
        int c4  = (f & 15) << 2;
        float4 v = *(const float4*)(src + (size_t)row * ld + c4);
        unsigned short h0 = f2bf(v.x), h1 = f2bf(v.y), h2 = f2bf(v.z), h3 = f2bf(v.w);
        short4v hv = { (short)h0, (short)h1, (short)h2, (short)h3 };
        short4v lv = { (short)f2bf(v.x - bf2f(h0)), (short)f2bf(v.y - bf2f(h1)),
                       (short)f2bf(v.z - bf2f(h2)), (short)f2bf(v.w - bf2f(h3)) };
        int sw = (row * 128 + (c4 << 1)) ^ ((row & 7) << 4);
        *(short4v*)(Lh + sw) = hv;
        *(short4v*)(Ll + sw) = lv;
    }
}
__device__ __forceinline__ void stage_sgn(const float* __restrict__ src, int ld,
                                          unsigned char* Lh, int tid) {
    #pragma unroll
    for (int it = 0; it < 8; ++it) {
        int f   = tid + it * 256;
        int row = f >> 4;
        int c4  = (f & 15) << 2;
        float4 v = *(const float4*)(src + (size_t)row * ld + c4);
        short4v hv = { sgnbf(v.x), sgnbf(v.y), sgnbf(v.z), sgnbf(v.w) };
        int sw = (row * 128 + (c4 << 1)) ^ ((row & 7) << 4);
        *(short4v*)(Lh + sw) = hv;
    }
}
// fragment: 8 contiguous bf16 at row, k = kk*32 + kg*8 (B^T-form, K-perm immune)
__device__ __forceinline__ s8v frag(const unsigned char* P, int row, int kk, int kg) {
    int byte = (row * 128 + kk * 64 + kg * 16) ^ ((row & 7) << 4);
    return *(const s8v*)(P + byte);
}

// ---------------------------------------------------------------------------
// K1: QKV projection via MFMA bf16x3.  C[t][j] = hid[t,:].W[j,:] + b[j].
// 128x128 tile, BK=64, 4 waves (2x2), 4x4 16x16 frags per wave.
// |v| < 1e-3 -> candidate appended for exact fp64 re-accumulation (K1b).
// ---------------------------------------------------------------------------
__global__ __launch_bounds__(256) void proj_mfma(
    const float* __restrict__ hid,
    const float* __restrict__ Wq, const float* __restrict__ bq,
    const float* __restrict__ Wk, const float* __restrict__ bk,
    const float* __restrict__ Wv, const float* __restrict__ bv,
    float* __restrict__ qkv,
    unsigned* __restrict__ cnt, unsigned* __restrict__ cand)
{
    __shared__ unsigned char sm[65536];   // Ah|Al|Bh|Bl, 16KB each
    const int nb    = blockIdx.x;         // 0..17
    const int which = nb / 6;
    const int jw0   = (nb % 6) * 128;
    const int t0    = blockIdx.y * 128;
    const float* W    = (which == 0) ? Wq : (which == 1) ? Wk : Wv;
    const float* bias = (which == 0) ? bq : (which == 1) ? bk : bv;

    const int tid  = threadIdx.x;
    const int lane = tid & 63;
    const int wv   = tid >> 6;
    const int wm   = wv >> 1, wn = wv & 1;
    const int r    = lane & 15, kg = lane >> 4;

    f32x4 acc[4][4] = {};
    for (int kb = 0; kb < HIDn; kb += 64) {
        stage_hl(hid + (size_t)t0  * HIDn + kb, HIDn, sm,         sm + 16384, tid);
        stage_hl(W   + (size_t)jw0 * HIDn + kb, HIDn, sm + 32768, sm + 49152, tid);
        __syncthreads();
        s8v bH[4][2], bL[4][2];
        #pragma unroll
        for (int n = 0; n < 4; ++n)
            #pragma unroll
            for (int kk = 0; kk < 2; ++kk) {
                int brow = wn * 64 + n * 16 + r;
                bH[n][kk] = frag(sm + 32768, brow, kk, kg);
                bL[n][kk] = frag(sm + 49152, brow, kk, kg);
            }
        #pragma unroll
        for (int m = 0; m < 4; ++m) {
            int arow = wm * 64 + m * 16 + r;
            s8v aH[2], aL[2];
            #pragma unroll
            for (int kk = 0; kk < 2; ++kk) {
                aH[kk] = frag(sm,         arow, kk, kg);
                aL[kk] = frag(sm + 16384, arow, kk, kg);
            }
            #pragma unroll
            for (int n = 0; n < 4; ++n)
                #pragma unroll
                for (int kk = 0; kk < 2; ++kk) {
                    acc[m][n] = MFMA(aH[kk], bH[n][kk], acc[m][n]);
                    acc[m][n] = MFMA(aH[kk], bL[n][kk], acc[m][n]);
                    acc[m][n] = MFMA(aL[kk], bH[n][kk], acc[m][n]);
                }
        }
        __syncthreads();
    }

    #pragma unroll
    for (int n = 0; n < 4; ++n) {
        const int jw = jw0 + wn * 64 + n * 16 + r;
        const float bs = bias[jw];
        #pragma unroll
        for (int m = 0; m < 4; ++m) {
            #pragma unroll
            for (int reg = 0; reg < 4; ++reg) {
                const int t = t0 + wm * 64 + m * 16 + kg * 4 + reg;
                float v = acc[m][n][reg] + bs;
                qkv[(size_t)which * (size_t)(Tn * HIDn) + (size_t)t * HIDn + jw] = v;
                if (fabsf(v) < 1e-3f) {
                    unsigned idx = atomicAdd(cnt, 1u);
                    if (idx < MAXCAND)
                        cand[idx] = (((unsigned)(which * Tn + t)) << 10) | (unsigned)jw;
                }
            }
        }
    }
}

// ---------------------------------------------------------------------------
// K1b: exact fp64 re-accumulation of near-zero projections.
// One wave per candidate; 768 products spread 12/lane (coalesced), fp64
// shuffle reduction. ~7.5k candidates expected -> a few microseconds.
// ---------------------------------------------------------------------------
__global__ __launch_bounds__(256) void refine_kernel(
    const float* __restrict__ hid,
    const float* __restrict__ Wq, const float* __restrict__ bq,
    const float* __restrict__ Wk, const float* __restrict__ bk,
    const float* __restrict__ Wv, const float* __restrict__ bv,
    const unsigned* __restrict__ cnt, const unsigned* __restrict__ cand,
    float* __restrict__ qkv)
{
    const int gwave = (blockIdx.x * 256 + threadIdx.x) >> 6;
    const int lane  = threadIdx.x & 63;
    const int nwave = gridDim.x * 4;
    const unsigned n = min(*cnt, MAXCAND);

    for (unsigned c = gwave; c < n; c += nwave) {
        const unsigned code = cand[c];
        const int jw    = code & 1023;
        const int wt    = code >> 10;          // which*Tn + t
        const int which = wt >> 12;
        const int t     = wt & (Tn - 1);
        const float* W    = (which == 0) ? Wq : (which == 1) ? Wk : Wv;
        const float* bias = (which == 0) ? bq : (which == 1) ? bk : bv;
        const float* ar = hid + (size_t)t * HIDn;
        const float* wr = W   + (size_t)jw * HIDn;
        double d = 0.0;
        #pragma unroll
        for (int i = 0; i < HIDn / 64; ++i)
            d += (double)ar[lane + i * 64] * (double)wr[lane + i * 64];
        #pragma unroll
        for (int off = 32; off; off >>= 1)
            d += __shfl_down(d, off, 64);
        if (lane == 0)
            qkv[(size_t)which * (size_t)(Tn * HIDn) + (size_t)t * HIDn + jw]
                = (float)(d + (double)bias[jw]);
    }
}

// ---------------------------------------------------------------------------
// K2: four S x S score planes per (b,h) via MFMA.
// which 0/1/2: bf16x3 (hi.hi + hi.lo + lo.hi) fp scores; which 3: exact
// sign(q).sign(k) single-term + mask. 128x128 tile, K=64 in one shot.
// ---------------------------------------------------------------------------
__global__ __launch_bounds__(256) void scores_mfma(
    const float* __restrict__ qkv, const float* __restrict__ mask,
    float* __restrict__ out)
{
    __shared__ unsigned char sm[65536];
    const int which = blockIdx.z;
    const int bh = blockIdx.y;
    const int b = bh / Hn, h = bh % Hn;
    const int s0 = (blockIdx.x >> 2) << 7;
    const int t0 = (blockIdx.x & 3) << 7;
    const int pa = (which == 3) ? 0 : which;
    const int pb = (which == 3) ? 1 : which;
    const float* Ap = qkv + (size_t)pa * (size_t)(Tn * HIDn) + (size_t)(b * Sn + s0) * HIDn + h * DHn;
    const float* Bp = qkv + (size_t)pb * (size_t)(Tn * HIDn) + (size_t)(b * Sn + t0) * HIDn + h * DHn;
    const int tid = threadIdx.x;
    const bool fp = (which != 3);

    if (fp) {
        stage_hl(Ap, HIDn, sm,         sm + 16384, tid);
        stage_hl(Bp, HIDn, sm + 32768, sm + 49152, tid);
    } else {
        stage_sgn(Ap, HIDn, sm,         tid);
        stage_sgn(Bp, HIDn, sm + 32768, tid);
    }
    __syncthreads();

    const int lane = tid & 63;
    const int wv   = tid >> 6;
    const int wm   = wv >> 1, wn = wv & 1;
    const int r    = lane & 15, kg = lane >> 4;

    f32x4 acc[4][4] = {};
    s8v bH[4][2], bL[4][2];
    #pragma unroll
    for (int n = 0; n < 4; ++n)
        #pragma unroll
        for (int kk = 0; kk < 2; ++kk) {
            int brow = wn * 64 + n * 16 + r;
            bH[n][kk] = frag(sm + 32768, brow, kk, kg);
            if (fp) bL[n][kk] = frag(sm + 49152, brow, kk, kg);
        }
    #pragma unroll
    for (int m = 0; m < 4; ++m) {
        int arow = wm * 64 + m * 16 + r;
        s8v aH[2], aL[2];
        #pragma unroll
        for (int kk = 0; kk < 2; ++kk) {
            aH[kk] = frag(sm, arow, kk, kg);
            if (fp) aL[kk] = frag(sm + 16384, arow, kk, kg);
        }
        #pragma unroll
        for (int n = 0; n < 4; ++n)
            #pragma unroll
            for (int kk = 0; kk < 2; ++kk) {
                acc[m][n] = MFMA(aH[kk], bH[n][kk], acc[m][n]);
                if (fp) {
                    acc[m][n] = MFMA(aH[kk], bL[n][kk], acc[m][n]);
                    acc[m][n] = MFMA(aL[kk], bH[n][kk], acc[m][n]);
                }
            }
    }

    const size_t plane = (which == 0) ? OFF_QRY : (which == 1) ? OFF_KEY
                       : (which == 2) ? OFF_VAL : OFF_ATTN;
    float* o = out + plane + (size_t)bh * (size_t)(Sn * Sn);
    #pragma unroll
    for (int n = 0; n < 4; ++n) {
        const int col = t0 + wn * 64 + n * 16 + r;
        const float mk = fp ? 0.f : mask[b * Sn + col];
        #pragma unroll
        for (int m = 0; m < 4; ++m) {
            #pragma unroll
            for (int reg = 0; reg < 4; ++reg) {
                const int srow = s0 + wm * 64 + m * 16 + kg * 4 + reg;
                o[(size_t)srow * Sn + col] = acc[m][n][reg] * 0.125f + mk;
            }
        }
    }
}

// ---------------------------------------------------------------------------
// K3: ctx = probs @ sign(V), probs = (attention_scores > 0) read back from out.
// fp32 vector version (known-good) — MFMA-ize next round if hot.
// ---------------------------------------------------------------------------
__global__ __launch_bounds__(256) void ctx_kernel(
    const float* __restrict__ qkv, const float* __restrict__ outc,
    float* __restrict__ out0)
{
    __shared__ float Ps[64][68];
    __shared__ float Vs[64][68];   // Vs[k][d]

    const int bh = blockIdx.y;
    const int b = bh / Hn, h = bh % Hn;
    const int s0 = blockIdx.x << 6;
    const float* sc = outc + OFF_ATTN + (size_t)bh * Sn * Sn;
    const float* Vp = qkv + 2ull * Tn * HIDn + (size_t)(b * Sn) * HIDn + h * DHn;

    const int tid = threadIdx.x;
    const int tx = tid & 15, ty = tid >> 4;
    float acc[4][4] = {};

    for (int kb = 0; kb < Sn; kb += 64) {
        #pragma unroll
        for (int l = 0; l < 4; ++l) {
            int f  = tid + l * 256;
            int r  = f >> 4;
            int c4 = (f & 15) << 2;
            float4 p = *(const float4*)(sc + (size_t)(s0 + r) * Sn + kb + c4);
            p.x = (p.x > 0.f) ? 1.f : 0.f;
            p.y = (p.y > 0.f) ? 1.f : 0.f;
            p.z = (p.z > 0.f) ? 1.f : 0.f;
            p.w = (p.w > 0.f) ? 1.f : 0.f;
            *(float4*)&Ps[r][c4] = p;
            float4 v = *(const float4*)(Vp + (size_t)(kb + r) * HIDn + c4);
            v.x = sgnf(v.x); v.y = sgnf(v.y); v.z = sgnf(v.z); v.w = sgnf(v.w);
            *(float4*)&Vs[r][c4] = v;
        }
        __syncthreads();
        #pragma unroll
        for (int k = 0; k < 64; ++k) {
            float p[4];
            #pragma unroll
            for (int i = 0; i < 4; ++i) p[i] = Ps[ty * 4 + i][k];
            float4 vv = *(const float4*)&Vs[k][tx * 4];
            #pragma unroll
            for (int i = 0; i < 4; ++i) {
                acc[i][0] = fmaf(p[i], vv.x, acc[i][0]);
                acc[i][1] = fmaf(p[i], vv.y, acc[i][1]);
                acc[i][2] = fmaf(p[i], vv.z, acc[i][2]);
                acc[i][3] = fmaf(p[i], vv.w, acc[i][3]);
            }
        }
        __syncthreads();
    }

    #pragma unroll
    for (int i = 0; i < 4; ++i) {
        const int srow = s0 + ty * 4 + i;
        float4 r4 = make_float4(acc[i][0], acc[i][1], acc[i][2], acc[i][3]);
        *(float4*)(out0 + (size_t)(b * Sn + srow) * HIDn + h * DHn + tx * 4) = r4;
    }
}

extern "C" void kernel_launch(void* const* d_in, const int* in_sizes, int n_in,
                              void* d_out, int out_size, void* d_ws, size_t ws_size,
                              hipStream_t stream)
{
    const float* hid  = (const float*)d_in[0];
    const float* mask = (const float*)d_in[1];
    const float* Wq   = (const float*)d_in[2];
    const float* bq   = (const float*)d_in[3];
    const float* Wk   = (const float*)d_in[4];
    const float* bk   = (const float*)d_in[5];
    const float* Wv   = (const float*)d_in[6];
    const float* bv   = (const float*)d_in[7];
    float* out = (float*)d_out;
    float* qkv = (float*)d_ws;                                   // 37.75 MB
    unsigned* cnt  = (unsigned*)((char*)d_ws + QKV_BYTES);       // 4 B (256 B slot)
    unsigned* cand = (unsigned*)((char*)d_ws + QKV_BYTES + 256); // 256 KB

    hipMemsetAsync(cnt, 0, 4, stream);

    dim3 blk(256);
    proj_mfma    <<<dim3(18, 32),    blk, 0, stream>>>(hid, Wq, bq, Wk, bk, Wv, bv, qkv, cnt, cand);
    refine_kernel<<<dim3(64),        blk, 0, stream>>>(hid, Wq, bq, Wk, bk, Wv, bv, cnt, cand, qkv);
    scores_mfma  <<<dim3(16, 96, 4), blk, 0, stream>>>(qkv, mask, out);
    ctx_kernel   <<<dim3(8, 96),     blk, 0, stream>>>(qkv, out, out);
}

// Round 4
// 349.249 us; speedup vs baseline: 3.8060x; 1.3964x over previous
//
#include <hip/hip_runtime.h>
#include <hip/hip_bf16.h>
#include <math.h>

#define Bn   8
#define Sn   512
#define HIDn 768
#define Hn   12
#define DHn  64
#define Tn   (Bn * Sn)   // 4096
#define NW   2304        // 3*768 W rows

// d_out float plane offsets (elements), return order:
// (context_layer, attention_scores, value_scores, query_scores, key_scores)
#define OFF_CTX   0ull
#define OFF_ATTN  3145728ull     // 8*512*768
#define OFF_VAL   28311552ull    // + 8*12*512*512
#define OFF_QRY   53477376ull
#define OFF_KEY   78643200ull

#define QKV_BYTES 37748736ull    // 3*4096*768*4
#define MAXCAND   65536u

typedef short  s8v     __attribute__((ext_vector_type(8)));
typedef short  short4v __attribute__((ext_vector_type(4)));
typedef unsigned short u8v __attribute__((ext_vector_type(8)));
typedef float  f32x4   __attribute__((ext_vector_type(4)));

typedef __attribute__((address_space(3))) unsigned int       lds_u32;
typedef __attribute__((address_space(1))) const unsigned int glb_u32;

#define MFMA(a, b, c) __builtin_amdgcn_mfma_f32_16x16x32_bf16((a), (b), (c), 0, 0, 0)

__device__ __forceinline__ float sgnf(float x) {
    return (x > 0.0f) ? 1.0f : ((x < 0.0f) ? -1.0f : 0.0f);
}
__device__ __forceinline__ unsigned short f2bf(float f) {   // RNE f32 -> bf16 bits
    unsigned int u = __float_as_uint(f);
    u += 0x7fffu + ((u >> 16) & 1u);
    return (unsigned short)(u >> 16);
}
__device__ __forceinline__ float bf2f(unsigned short h) {
    return __uint_as_float(((unsigned int)h) << 16);
}
__device__ __forceinline__ short sgnbf(float x) {           // bf16 bits of sign(x)
    return x > 0.f ? (short)0x3F80 : (x < 0.f ? (short)0xBF80 : (short)0);
}

// ---------------------------------------------------------------------------
// P0: one-pass fp32 -> (bf16 hi, bf16 lo) convert + PRE-SWIZZLE (k ^= (row&7)<<3,
// i.e. byte ^= (row&7)<<4). proj then stages with linear global_load_lds and
// reads fragments with the XOR — composes to identity (rule: linear dest +
// inverse-swz source + swz read).
// ---------------------------------------------------------------------------
__global__ __launch_bounds__(256) void prep_kernel(
    const float* __restrict__ hid,
    const float* __restrict__ Wq, const float* __restrict__ Wk, const float* __restrict__ Wv,
    unsigned short* __restrict__ hidH, unsigned short* __restrict__ hidL,
    unsigned short* __restrict__ WH,   unsigned short* __restrict__ WL)
{
    const int NCH_HID = Tn * (HIDn / 8);      // 393216 16B-chunks
    const int NCH_W   = NW * (HIDn / 8);      // 221184
    const int total   = NCH_HID + NCH_W;
    for (int c = blockIdx.x * 256 + threadIdx.x; c < total; c += gridDim.x * 256) {
        const float* src; unsigned short *dH, *dL; int row, kc;
        if (c < NCH_HID) {
            row = c / 96; kc = c % 96;
            src = hid + (size_t)row * HIDn + kc * 8;
            dH = hidH; dL = hidL;
        } else {
            int c2 = c - NCH_HID;
            row = c2 / 96; kc = c2 % 96;
            const int which = row / HIDn, jw = row % HIDn;
            const float* W = (which == 0) ? Wq : (which == 1) ? Wk : Wv;
            src = W + (size_t)jw * HIDn + kc * 8;
            dH = WH; dL = WL;
        }
        float4 a = *(const float4*)src;
        float4 b = *(const float4*)(src + 4);
        const float f[8] = {a.x, a.y, a.z, a.w, b.x, b.y, b.z, b.w};
        u8v hv, lv;
        #pragma unroll
        for (int i = 0; i < 8; ++i) {
            unsigned short h = f2bf(f[i]);
            hv[i] = h;
            lv[i] = f2bf(f[i] - bf2f(h));
        }
        const int ks = (kc * 8) ^ ((row & 7) << 3);   // swizzled element pos
        *(u8v*)(dH + (size_t)row * HIDn + ks) = hv;
        *(u8v*)(dL + (size_t)row * HIDn + ks) = lv;
    }
}

// fragment: 8 contiguous bf16 at (row, k=kk*32+kg*8), XOR-swizzled LDS
__device__ __forceinline__ s8v frag(const unsigned char* P, int row, int kk, int kg) {
    int byte = (row * 128 + kk * 64 + kg * 16) ^ ((row & 7) << 4);
    return *(const s8v*)(P + byte);
}

// stage one 128x64 bf16 tile (16KB) from pre-swizzled plane via global_load_lds.
// wave wv copies chunks [wv*4, wv*4+4): dest = ldsbase + chunk*1024 (+lane*16 by HW),
// source = per-lane address in the row-strided global plane.
__device__ __forceinline__ void gload_tile(const unsigned short* __restrict__ srcbase,
                                           unsigned char* ldsbase, int wv, int lane) {
    #pragma unroll
    for (int i = 0; i < 4; ++i) {
        const int chunk = wv * 4 + i;
        const int off = chunk * 1024 + lane * 16;     // byte within 128x128B tile
        const int row = off >> 7, bir = off & 127;
        const unsigned short* g = srcbase + (size_t)row * HIDn + (bir >> 1);
        __builtin_amdgcn_global_load_lds((glb_u32*)g, (lds_u32*)(ldsbase + chunk * 1024),
                                         16, 0, 0);
    }
}

// ---------------------------------------------------------------------------
// K1: QKV projection via MFMA bf16x3 from pre-converted swizzled planes.
// 128x128 tile, BK=64, 4 waves (2x2), 4x4 16x16 frags per wave.
// |v| < 1e-3 -> candidate appended for exact fp64 re-accumulation (K1b).
// ---------------------------------------------------------------------------
__global__ __launch_bounds__(256) void proj_mfma(
    const unsigned short* __restrict__ hidH, const unsigned short* __restrict__ hidL,
    const unsigned short* __restrict__ WH,   const unsigned short* __restrict__ WL,
    const float* __restrict__ bq, const float* __restrict__ bk, const float* __restrict__ bv,
    float* __restrict__ qkv,
    unsigned* __restrict__ cnt, unsigned* __restrict__ cand)
{
    __shared__ unsigned char sm[65536];   // Ah|Al|Bh|Bl, 16KB each
    const int nb    = blockIdx.x;         // 0..17
    const int which = nb / 6;
    const int jw0   = (nb % 6) * 128;
    const int t0    = blockIdx.y * 128;
    const float* bias = (which == 0) ? bq : (which == 1) ? bk : bv;
    const int wrow0 = which * HIDn + jw0; // row in concatenated W planes

    const int tid  = threadIdx.x;
    const int lane = tid & 63;
    const int wv   = tid >> 6;
    const int wm   = wv >> 1, wn = wv & 1;
    const int r    = lane & 15, kg = lane >> 4;

    f32x4 acc[4][4] = {};
    for (int kb = 0; kb < HIDn; kb += 64) {
        gload_tile(hidH + (size_t)t0 * HIDn + kb,    sm,         wv, lane);
        gload_tile(hidL + (size_t)t0 * HIDn + kb,    sm + 16384, wv, lane);
        gload_tile(WH   + (size_t)wrow0 * HIDn + kb, sm + 32768, wv, lane);
        gload_tile(WL   + (size_t)wrow0 * HIDn + kb, sm + 49152, wv, lane);
        __syncthreads();   // drains vmcnt (global_load_lds) + lgkm

        s8v bH[4][2], bL[4][2];
        #pragma unroll
        for (int n = 0; n < 4; ++n)
            #pragma unroll
            for (int kk = 0; kk < 2; ++kk) {
                int brow = wn * 64 + n * 16 + r;
                bH[n][kk] = frag(sm + 32768, brow, kk, kg);
                bL[n][kk] = frag(sm + 49152, brow, kk, kg);
            }
        #pragma unroll
        for (int m = 0; m < 4; ++m) {
            int arow = wm * 64 + m * 16 + r;
            s8v aH[2], aL[2];
            #pragma unroll
            for (int kk = 0; kk < 2; ++kk) {
                aH[kk] = frag(sm,         arow, kk, kg);
                aL[kk] = frag(sm + 16384, arow, kk, kg);
            }
            #pragma unroll
            for (int n = 0; n < 4; ++n)
                #pragma unroll
                for (int kk = 0; kk < 2; ++kk) {
                    acc[m][n] = MFMA(aH[kk], bH[n][kk], acc[m][n]);
                    acc[m][n] = MFMA(aH[kk], bL[n][kk], acc[m][n]);
                    acc[m][n] = MFMA(aL[kk], bH[n][kk], acc[m][n]);
                }
        }
        __syncthreads();
    }

    #pragma unroll
    for (int n = 0; n < 4; ++n) {
        const int jw = jw0 + wn * 64 + n * 16 + r;
        const float bs = bias[jw];
        #pragma unroll
        for (int m = 0; m < 4; ++m) {
            #pragma unroll
            for (int reg = 0; reg < 4; ++reg) {
                const int t = t0 + wm * 64 + m * 16 + kg * 4 + reg;
                float v = acc[m][n][reg] + bs;
                qkv[(size_t)which * (size_t)(Tn * HIDn) + (size_t)t * HIDn + jw] = v;
                if (fabsf(v) < 1e-3f) {
                    unsigned idx = atomicAdd(cnt, 1u);
                    if (idx < MAXCAND)
                        cand[idx] = (((unsigned)(which * Tn + t)) << 10) | (unsigned)jw;
                }
            }
        }
    }
}

// ---------------------------------------------------------------------------
// K1b: exact fp64 re-accumulation of near-zero projections.
// One wave per candidate; 768 products spread 12/lane (coalesced), fp64
// shuffle reduction. ~7.5k candidates expected -> a few microseconds.
// ---------------------------------------------------------------------------
__global__ __launch_bounds__(256) void refine_kernel(
    const float* __restrict__ hid,
    const float* __restrict__ Wq, const float* __restrict__ bq,
    const float* __restrict__ Wk, const float* __restrict__ bk,
    const float* __restrict__ Wv, const float* __restrict__ bv,
    const unsigned* __restrict__ cnt, const unsigned* __restrict__ cand,
    float* __restrict__ qkv)
{
    const int gwave = (blockIdx.x * 256 + threadIdx.x) >> 6;
    const int lane  = threadIdx.x & 63;
    const int nwave = gridDim.x * 4;
    const unsigned n = min(*cnt, MAXCAND);

    for (unsigned c = gwave; c < n; c += nwave) {
        const unsigned code = cand[c];
        const int jw    = code & 1023;
        const int wt    = code >> 10;          // which*Tn + t
        const int which = wt >> 12;
        const int t     = wt & (Tn - 1);
        const float* W    = (which == 0) ? Wq : (which == 1) ? Wk : Wv;
        const float* bias = (which == 0) ? bq : (which == 1) ? bk : bv;
        const float* ar = hid + (size_t)t * HIDn;
        const float* wr = W   + (size_t)jw * HIDn;
        double d = 0.0;
        #pragma unroll
        for (int i = 0; i < HIDn / 64; ++i)
            d += (double)ar[lane + i * 64] * (double)wr[lane + i * 64];
        #pragma unroll
        for (int off = 32; off; off >>= 1)
            d += __shfl_down(d, off, 64);
        if (lane == 0)
            qkv[(size_t)which * (size_t)(Tn * HIDn) + (size_t)t * HIDn + jw]
                = (float)(d + (double)bias[jw]);
    }
}

// ---------------------------------------------------------------------------
// LDS tile staging with on-the-fly convert (still used by scores_mfma).
// ---------------------------------------------------------------------------
__device__ __forceinline__ void stage_hl(const float* __restrict__ src, int ld,
                                         unsigned char* Lh, unsigned char* Ll, int tid) {
    #pragma unroll
    for (int it = 0; it < 8; ++it) {
        int f   = tid + it * 256;          // 0..2047 -> 128 rows x 16 float4
        int row = f >> 4;
        int c4  = (f & 15) << 2;
        float4 v = *(const float4*)(src + (size_t)row * ld + c4);
        unsigned short h0 = f2bf(v.x), h1 = f2bf(v.y), h2 = f2bf(v.z), h3 = f2bf(v.w);
        short4v hv = { (short)h0, (short)h1, (short)h2, (short)h3 };
        short4v lv = { (short)f2bf(v.x - bf2f(h0)), (short)f2bf(v.y - bf2f(h1)),
                       (short)f2bf(v.z - bf2f(h2)), (short)f2bf(v.w - bf2f(h3)) };
        int sw = (row * 128 + (c4 << 1)) ^ ((row & 7) << 4);
        *(short4v*)(Lh + sw) = hv;
        *(short4v*)(Ll + sw) = lv;
    }
}
__device__ __forceinline__ void stage_sgn(const float* __restrict__ src, int ld,
                                          unsigned char* Lh, int tid) {
    #pragma unroll
    for (int it = 0; it < 8; ++it) {
        int f   = tid + it * 256;
        int row = f >> 4;
        int c4  = (f & 15) << 2;
        float4 v = *(const float4*)(src + (size_t)row * ld + c4);
        short4v hv = { sgnbf(v.x), sgnbf(v.y), sgnbf(v.z), sgnbf(v.w) };
        int sw = (row * 128 + (c4 << 1)) ^ ((row & 7) << 4);
        *(short4v*)(Lh + sw) = hv;
    }
}

// ---------------------------------------------------------------------------
// K2: four S x S score planes per (b,h) via MFMA.
// which 0/1/2: bf16x3 (hi.hi + hi.lo + lo.hi) fp scores; which 3: exact
// sign(q).sign(k) single-term + mask. 128x128 tile, K=64 in one shot.
// ---------------------------------------------------------------------------
__global__ __launch_bounds__(256) void scores_mfma(
    const float* __restrict__ qkv, const float* __restrict__ mask,
    float* __restrict__ out)
{
    __shared__ unsigned char sm[65536];
    const int which = blockIdx.z;
    const int bh = blockIdx.y;
    const int b = bh / Hn, h = bh % Hn;
    const int s0 = (blockIdx.x >> 2) << 7;
    const int t0 = (blockIdx.x & 3) << 7;
    const int pa = (which == 3) ? 0 : which;
    const int pb = (which == 3) ? 1 : which;
    const float* Ap = qkv + (size_t)pa * (size_t)(Tn * HIDn) + (size_t)(b * Sn + s0) * HIDn + h * DHn;
    const float* Bp = qkv + (size_t)pb * (size_t)(Tn * HIDn) + (size_t)(b * Sn + t0) * HIDn + h * DHn;
    const int tid = threadIdx.x;
    const bool fp = (which != 3);

    if (fp) {
        stage_hl(Ap, HIDn, sm,         sm + 16384, tid);
        stage_hl(Bp, HIDn, sm + 32768, sm + 49152, tid);
    } else {
        stage_sgn(Ap, HIDn, sm,         tid);
        stage_sgn(Bp, HIDn, sm + 32768, tid);
    }
    __syncthreads();

    const int lane = tid & 63;
    const int wv   = tid >> 6;
    const int wm   = wv >> 1, wn = wv & 1;
    const int r    = lane & 15, kg = lane >> 4;

    f32x4 acc[4][4] = {};
    s8v bH[4][2], bL[4][2];
    #pragma unroll
    for (int n = 0; n < 4; ++n)
        #pragma unroll
        for (int kk = 0; kk < 2; ++kk) {
            int brow = wn * 64 + n * 16 + r;
            bH[n][kk] = frag(sm + 32768, brow, kk, kg);
            if (fp) bL[n][kk] = frag(sm + 49152, brow, kk, kg);
        }
    #pragma unroll
    for (int m = 0; m < 4; ++m) {
        int arow = wm * 64 + m * 16 + r;
        s8v aH[2], aL[2];
        #pragma unroll
        for (int kk = 0; kk < 2; ++kk) {
            aH[kk] = frag(sm, arow, kk, kg);
            if (fp) aL[kk] = frag(sm + 16384, arow, kk, kg);
        }
        #pragma unroll
        for (int n = 0; n < 4; ++n)
            #pragma unroll
            for (int kk = 0; kk < 2; ++kk) {
                acc[m][n] = MFMA(aH[kk], bH[n][kk], acc[m][n]);
                if (fp) {
                    acc[m][n] = MFMA(aH[kk], bL[n][kk], acc[m][n]);
                    acc[m][n] = MFMA(aL[kk], bH[n][kk], acc[m][n]);
                }
            }
    }

    const size_t plane = (which == 0) ? OFF_QRY : (which == 1) ? OFF_KEY
                       : (which == 2) ? OFF_VAL : OFF_ATTN;
    float* o = out + plane + (size_t)bh * (size_t)(Sn * Sn);
    #pragma unroll
    for (int n = 0; n < 4; ++n) {
        const int col = t0 + wn * 64 + n * 16 + r;
        const float mk = fp ? 0.f : mask[b * Sn + col];
        #pragma unroll
        for (int m = 0; m < 4; ++m) {
            #pragma unroll
            for (int reg = 0; reg < 4; ++reg) {
                const int srow = s0 + wm * 64 + m * 16 + kg * 4 + reg;
                o[(size_t)srow * Sn + col] = acc[m][n][reg] * 0.125f + mk;
            }
        }
    }
}

// ---------------------------------------------------------------------------
// K3: ctx = probs @ sign(V), probs = (attention_scores > 0) read back from out.
// ---------------------------------------------------------------------------
__global__ __launch_bounds__(256) void ctx_kernel(
    const float* __restrict__ qkv, const float* __restrict__ outc,
    float* __restrict__ out0)
{
    __shared__ float Ps[64][68];
    __shared__ float Vs[64][68];   // Vs[k][d]

    const int bh = blockIdx.y;
    const int b = bh / Hn, h = bh % Hn;
    const int s0 = blockIdx.x << 6;
    const float* sc = outc + OFF_ATTN + (size_t)bh * Sn * Sn;
    const float* Vp = qkv + 2ull * Tn * HIDn + (size_t)(b * Sn) * HIDn + h * DHn;

    const int tid = threadIdx.x;
    const int tx = tid & 15, ty = tid >> 4;
    float acc[4][4] = {};

    for (int kb = 0; kb < Sn; kb += 64) {
        #pragma unroll
        for (int l = 0; l < 4; ++l) {
            int f  = tid + l * 256;
            int r  = f >> 4;
            int c4 = (f & 15) << 2;
            float4 p = *(const float4*)(sc + (size_t)(s0 + r) * Sn + kb + c4);
            p.x = (p.x > 0.f) ? 1.f : 0.f;
            p.y = (p.y > 0.f) ? 1.f : 0.f;
            p.z = (p.z > 0.f) ? 1.f : 0.f;
            p.w = (p.w > 0.f) ? 1.f : 0.f;
            *(float4*)&Ps[r][c4] = p;
            float4 v = *(const float4*)(Vp + (size_t)(kb + r) * HIDn + c4);
            v.x = sgnf(v.x); v.y = sgnf(v.y); v.z = sgnf(v.z); v.w = sgnf(v.w);
            *(float4*)&Vs[r][c4] = v;
        }
        __syncthreads();
        #pragma unroll
        for (int k = 0; k < 64; ++k) {
            float p[4];
            #pragma unroll
            for (int i = 0; i < 4; ++i) p[i] = Ps[ty * 4 + i][k];
            float4 vv = *(const float4*)&Vs[k][tx * 4];
            #pragma unroll
            for (int i = 0; i < 4; ++i) {
                acc[i][0] = fmaf(p[i], vv.x, acc[i][0]);
                acc[i][1] = fmaf(p[i], vv.y, acc[i][1]);
                acc[i][2] = fmaf(p[i], vv.z, acc[i][2]);
                acc[i][3] = fmaf(p[i], vv.w, acc[i][3]);
            }
        }
        __syncthreads();
    }

    #pragma unroll
    for (int i = 0; i < 4; ++i) {
        const int srow = s0 + ty * 4 + i;
        float4 r4 = make_float4(acc[i][0], acc[i][1], acc[i][2], acc[i][3]);
        *(float4*)(out0 + (size_t)(b * Sn + srow) * HIDn + h * DHn + tx * 4) = r4;
    }
}

extern "C" void kernel_launch(void* const* d_in, const int* in_sizes, int n_in,
                              void* d_out, int out_size, void* d_ws, size_t ws_size,
                              hipStream_t stream)
{
    const float* hid  = (const float*)d_in[0];
    const float* mask = (const float*)d_in[1];
    const float* Wq   = (const float*)d_in[2];
    const float* bq   = (const float*)d_in[3];
    const float* Wk   = (const float*)d_in[4];
    const float* bk   = (const float*)d_in[5];
    const float* Wv   = (const float*)d_in[6];
    const float* bv   = (const float*)d_in[7];
    float* out = (float*)d_out;
    float* qkv = (float*)d_ws;                                   // 37.75 MB
    unsigned* cnt  = (unsigned*)((char*)d_ws + QKV_BYTES);       // 4 B (256 B slot)
    unsigned* cand = (unsigned*)((char*)d_ws + QKV_BYTES + 256); // 256 KB

    // bf16 hi/lo swizzled planes, scratch inside d_out's QRY plane
    // (consumed by proj_mfma BEFORE scores_mfma overwrites the plane).
    unsigned short* hidH = (unsigned short*)(out + OFF_QRY);
    unsigned short* hidL = hidH + (size_t)Tn * HIDn;
    unsigned short* WH   = hidL + (size_t)Tn * HIDn;
    unsigned short* WL   = WH   + (size_t)NW * HIDn;

    hipMemsetAsync(cnt, 0, 4, stream);

    dim3 blk(256);
    prep_kernel  <<<dim3(2048),      blk, 0, stream>>>(hid, Wq, Wk, Wv, hidH, hidL, WH, WL);
    proj_mfma    <<<dim3(18, 32),    blk, 0, stream>>>(hidH, hidL, WH, WL, bq, bk, bv, qkv, cnt, cand);
    refine_kernel<<<dim3(64),        blk, 0, stream>>>(hid, Wq, bq, Wk, bk, Wv, bv, cnt, cand, qkv);
    scores_mfma  <<<dim3(16, 96, 4), blk, 0, stream>>>(qkv, mask, out);
    ctx_kernel   <<<dim3(8, 96),     blk, 0, stream>>>(qkv, out, out);
}